// Round 2
// baseline (365.857 us; speedup 1.0000x reference)
//
#include <hip/hip_runtime.h>
#include <math.h>

// LSTM fused: H=32, D=1, B=4096, T=1024 — R14: 2 waves/SIMD + E/O lane split.
//
// R13 law: latency-bound at 1 wave/SIMD (wall 780 cyc/step = 485 busy + 300
// chain stall). Cutting instructions no longer pays; filling stalls does.
// R14:
//   1. BPW=2 -> 2048 waves = 2 waves/SIMD; independent recurrence chains
//      interleave, stalls of one wave absorb issue of the other.
//      batch(A-row m) = m>>3; D rows 4q..4q+3 still single-batch (=q>>1),
//      so gate values stay at acc[tau][0] — zero extraction preserved.
//   2. E/O split: at BPW=2 lanes l and l+16 hold identical acc data.
//      Lane parity p=q&1 picks unit u=2n+p; each lane runs ONE state ->
//      7 trans/step (5 exp2 + 2 rcp) and 4 preact fmaf, half of R13.
//      Gate select = 4 cndmask vs hoisted parity mask.
//   3. Exchange: h kept as f32; A-frag gathered with 8 ds_bpermute
//      (4 E-lanes 32b+4q+i, 4 O-lanes +16) + 4 cvt_pkrtz. One DS hop on
//      the chain (same as R13), pack step gone.
// Rational fused acts (R13) unchanged: c' = (c*u*v + w*(2-v))/(u*v*w),
// h = (1-m)/((1+e)(1+m)), -L/-2L folded into weights/consts.
// 512 blocks x 4 waves, 2 blocks/CU, 16 KB LDS/block.

#define HH 32
#define TT 1024
#define BPW 2               // batches per wave
#define WPB 4               // waves per block
#define BPB (BPW * WPB)     // 8
#define NT 256

typedef _Float16 half8 __attribute__((ext_vector_type(8)));
typedef float    f32x4 __attribute__((ext_vector_type(4)));
typedef int      int4v __attribute__((ext_vector_type(4)));

__global__ __attribute__((amdgpu_flat_work_group_size(NT, NT),
                          amdgpu_waves_per_eu(2, 2)))
void lstm_vp(const float* __restrict__ x,
             const float* __restrict__ W_ih,
             const float* __restrict__ W_hh,
             const float* __restrict__ b_ih,
             const float* __restrict__ b_hh,
             const float* __restrict__ fc_W,
             const float* __restrict__ fc_b,
             float* __restrict__ out)
{
    __shared__ _Float16 xw[WPB][BPW * TT];   // 16 KB: x fp16, wave-private

    const int tid  = threadIdx.x;
    const int wv   = tid >> 6;
    const int lane = tid & 63;
    const int q    = lane >> 4;          // k-group (0..3)
    const int n    = lane & 15;          // unit-pair index (0..15)
    const int beta = q >> 1;             // this lane's act batch (0..1)
    const int p    = q & 1;              // parity: 0 -> unit 2n, 1 -> 2n+1
    const int u    = 2 * n + p;          // owned unit
    const int gb0  = blockIdx.x * BPB + wv * BPW;

    // ---- stage this wave's 2 x-rows into LDS as fp16 (wave-private) ----
    {
        const float4* xg = (const float4*)(x + (size_t)gb0 * TT);
        #pragma unroll
        for (int it = 0; it < (BPW * TT / 4) / 64; ++it) {
            const float4 v = xg[it * 64 + lane];
            _Float16* dst = &xw[wv][(it * 64 + lane) * 4];
            dst[0] = (_Float16)v.x; dst[1] = (_Float16)v.y;
            dst[2] = (_Float16)v.z; dst[3] = (_Float16)v.w;
        }
    }

    const float L1 = 1.4426950408889634f;    // log2(e)

    // ---- B-fragments: pair-permuted weights, pre-scaled by -L (i,f,o)
    //      or -2L (g). Tile tau=2g+pp, col n = W_hh row 32g+2n+pp;
    //      lane supplies B[k=8q+j][n]. ----
    half8 wf[8];
    #pragma unroll
    for (int g = 0; g < 4; ++g) {
        const float s = (g == 2) ? -2.0f * L1 : -L1;
        #pragma unroll
        for (int pp = 0; pp < 2; ++pp) {
            const float* arow = W_hh + (size_t)(32 * g + 2 * n + pp) * HH + 8 * q;
            #pragma unroll
            for (int j = 0; j < 8; ++j)
                wf[2 * g + pp][j] = (_Float16)(arow[j] * s);
        }
    }

    // ---- per-lane act constants for the single owned unit u ----
    float wx[4], bb[4];
    #pragma unroll
    for (int g = 0; g < 4; ++g) {
        const float s = (g == 2) ? -2.0f * L1 : -L1;
        wx[g] = W_ih[g * HH + u] * s;
        bb[g] = (b_ih[g * HH + u] + b_hh[g * HH + u]) * s;
    }

    // bpermute byte addrs: A row m = n (this lane), batch m>>3; k-units
    // 8q..8q+7 = pairs 4q..4q+3; E-source lane 32*(n>>3)+4q+i, O = +16.
    const int bpE = ((32 * (n >> 3) + 4 * q) << 2);
    const bool pb = (p != 0);

    float c = 0.0f, h = 0.0f;

    const half8* xp = (const half8*)&xw[wv][beta * TT];
    half8 xcur = xp[0];

    #pragma unroll 1
    for (int tc = 0; tc < TT / 8; ++tc) {
        const half8 xv8 = xcur;
        xcur = xp[(tc + 1) & (TT / 8 - 1)];   // prefetch next chunk (off-chain)

        #pragma unroll
        for (int tt = 0; tt < 8; ++tt) {
            // ---- h exchange: gather f32 h from 4 E-lanes + 4 O-lanes ----
            const int hb = __builtin_bit_cast(int, h);
            const int e0 = __builtin_amdgcn_ds_bpermute(bpE,      hb);
            const int e1 = __builtin_amdgcn_ds_bpermute(bpE + 4,  hb);
            const int e2 = __builtin_amdgcn_ds_bpermute(bpE + 8,  hb);
            const int e3 = __builtin_amdgcn_ds_bpermute(bpE + 12, hb);
            const int o0 = __builtin_amdgcn_ds_bpermute(bpE + 64, hb);
            const int o1 = __builtin_amdgcn_ds_bpermute(bpE + 68, hb);
            const int o2 = __builtin_amdgcn_ds_bpermute(bpE + 72, hb);
            const int o3 = __builtin_amdgcn_ds_bpermute(bpE + 76, hb);

            // ---- preact input part, OFF the chain (hides bpermute lat) ----
            const float xv = (float)xv8[tt];
            float qq[4];
            #pragma unroll
            for (int g = 0; g < 4; ++g)
                qq[g] = fmaf(xv, wx[g], bb[g]);

            int4v ai;
            ai[0] = __builtin_bit_cast(int, __builtin_amdgcn_cvt_pkrtz(
                        __builtin_bit_cast(float, e0), __builtin_bit_cast(float, o0)));
            ai[1] = __builtin_bit_cast(int, __builtin_amdgcn_cvt_pkrtz(
                        __builtin_bit_cast(float, e1), __builtin_bit_cast(float, o1)));
            ai[2] = __builtin_bit_cast(int, __builtin_amdgcn_cvt_pkrtz(
                        __builtin_bit_cast(float, e2), __builtin_bit_cast(float, o2)));
            ai[3] = __builtin_bit_cast(int, __builtin_amdgcn_cvt_pkrtz(
                        __builtin_bit_cast(float, e3), __builtin_bit_cast(float, o3)));
            const half8 av = __builtin_bit_cast(half8, ai);

            const f32x4 zero = {0.0f, 0.0f, 0.0f, 0.0f};
            f32x4 acc[8];
            #pragma unroll
            for (int tau = 0; tau < 8; ++tau) {
                acc[tau] = __builtin_amdgcn_mfma_f32_16x16x32_f16(
                               av, wf[tau], zero, 0, 0, 0);
                asm("" : "+v"(acc[tau]));   // pin quad to arch VGPRs
            }

            // ---- gate select by parity: 4 cndmask, zero extraction ----
            const float vi = pb ? acc[1][0] : acc[0][0];
            const float vf = pb ? acc[3][0] : acc[2][0];
            const float vg = pb ? acc[5][0] : acc[4][0];
            const float vo = pb ? acc[7][0] : acc[6][0];

            // ---- exp2 args (weights pre-scaled by -L / -2L) ----
            const float ea = __builtin_amdgcn_exp2f(vi + qq[0]);  // e^-i
            const float eb = __builtin_amdgcn_exp2f(vf + qq[1]);  // e^-f
            const float ed = __builtin_amdgcn_exp2f(vg + qq[2]);  // e^-2g
            const float ee = __builtin_amdgcn_exp2f(vo + qq[3]);  // e^-o

            // ---- c' = (c*u*v + w*(2-v)) / (u*v*w); one rcp ----
            const float uu = 1.0f + ea, vv = 1.0f + ed, ww = 1.0f + eb;
            const float uv  = uu * vv;
            const float num = fmaf(c, uv, ww * (2.0f - vv));
            c = num * __builtin_amdgcn_rcpf(uv * ww);
            c = fminf(fmaxf(c, -32.0f), 32.0f);   // guard m-overflow

            // ---- h = (1-m)/((1+e)(1+m)), m = e^-2c; one rcp ----
            const float m = __builtin_amdgcn_exp2f(c * (-2.0f * L1));
            h = (1.0f - m) * __builtin_amdgcn_rcpf((1.0f + ee) * (1.0f + m));
        }
    }

    // ---- epilogue: out[gb0+beta] = fc_W . h + fc_b; reduce 32 lanes ----
    float pr = h * fc_W[u];
    pr += __shfl_xor(pr, 1, 64);
    pr += __shfl_xor(pr, 2, 64);
    pr += __shfl_xor(pr, 4, 64);
    pr += __shfl_xor(pr, 8, 64);
    pr += __shfl_xor(pr, 16, 64);
    if ((lane & 31) == 0)
        out[gb0 + beta] = pr + fc_b[0];
}

extern "C" void kernel_launch(void* const* d_in, const int* in_sizes, int n_in,
                              void* d_out, int out_size, void* d_ws, size_t ws_size,
                              hipStream_t stream) {
    const float* x    = (const float*)d_in[0];
    const float* W_ih = (const float*)d_in[1];
    const float* W_hh = (const float*)d_in[2];
    const float* b_ih = (const float*)d_in[3];
    const float* b_hh = (const float*)d_in[4];
    const float* fc_W = (const float*)d_in[5];
    const float* fc_b = (const float*)d_in[6];
    float* out = (float*)d_out;

    const int B = in_sizes[0] / TT;   // 4096 (D == 1)
    dim3 grid(B / BPB), block(NT);
    lstm_vp<<<grid, block, 0, stream>>>(x, W_ih, W_hh, b_ih, b_hh,
                                        fc_W, fc_b, out);
}